// Round 8
// baseline (167.067 us; speedup 1.0000x reference)
//
#include <hip/hip_runtime.h>

#define D 64
#define H 128
#define BN 128            // nodes per bucket
#define CAP 3456          // per-bucket edge capacity (avg 2558, +17 sigma)
#define NBB 512           // partition blocks

typedef short bf16x8 __attribute__((ext_vector_type(8)));
typedef float f32x4  __attribute__((ext_vector_type(4)));
typedef float f32x2  __attribute__((ext_vector_type(2)));

__device__ __forceinline__ ushort f2bf(float f) {
    unsigned u = __float_as_uint(f);
    unsigned r = (u + 0x7FFFu + ((u >> 16) & 1u)) >> 16;
    return (ushort)r;
}

__device__ __forceinline__ bf16x8 pack8(float4 a, float4 b) {
    ushort o[8];
    o[0]=f2bf(a.x); o[1]=f2bf(a.y); o[2]=f2bf(a.z); o[3]=f2bf(a.w);
    o[4]=f2bf(b.x); o[5]=f2bf(b.y); o[6]=f2bf(b.z); o[7]=f2bf(b.w);
    bf16x8 r;
    __builtin_memcpy(&r, o, 16);
    return r;
}

// unpack 2 packed bf16 -> f32x2 (lowered to shl/and + v_pk_add_f32 at the use)
__device__ __forceinline__ f32x2 unp(unsigned u) {
    f32x2 v;
    v.x = __uint_as_float(u << 16);
    v.y = __uint_as_float(u & 0xFFFF0000u);
    return v;
}

// ---------------------------------------------------------------------------
// 0) prep_p: x_prot f32 -> bf16 row-major
// ---------------------------------------------------------------------------
__global__ void prep_p_kernel(const float* __restrict__ xp, ushort* __restrict__ xpb,
                              int total) {
    int i = (blockIdx.x * 256 + threadIdx.x) * 8;
    if (i >= total) return;
    float4 a = *(const float4*)(xp + i);
    float4 b = *(const float4*)(xp + i + 4);
    bf16x8 v = pack8(a, b);
    *(bf16x8*)(xpb + i) = v;
}

// ---------------------------------------------------------------------------
// 1) prep_w: pack [Wl;Wr] into MFMA B-fragment bf16 layout
// ---------------------------------------------------------------------------
__global__ void prep_w_kernel(const float* __restrict__ Wl, const float* __restrict__ Wr,
                              ushort* __restrict__ wprep) {
    int e = blockIdx.x * 256 + threadIdx.x;
    if (e >= 2048) return;
    int lane = e & 63;
    int ks = (e >> 6) & 3;
    int ht = e >> 8;
    int h = ht * 16 + (lane & 15);
    int k0 = ks * 32 + (lane >> 4) * 8;
    ushort o[8];
    #pragma unroll
    for (int j = 0; j < 8; ++j) {
        int k = k0 + j;
        float v = (k < D) ? Wl[k * H + h] : Wr[(k - D) * H + h];
        o[j] = f2bf(v);
    }
    *(bf16x8*)(wprep + (size_t)e * 8) = *(bf16x8*)o;
}

// ---------------------------------------------------------------------------
// 2a) part_hist: per-block LDS histogram of dst buckets -> cnt[block][bucket]
// ---------------------------------------------------------------------------
__global__ __launch_bounds__(256)
void part_hist_kernel(const int* __restrict__ dst, int* __restrict__ cnt,
                      int E, int K, int ce) {
    __shared__ int scnt[800];
    int t = threadIdx.x;
    for (int b = t; b < K; b += 256) scnt[b] = 0;
    __syncthreads();
    int e0 = blockIdx.x * ce;
    int e1 = min(E, e0 + ce);
    for (int i = e0 + t * 4; i < e1; i += 1024) {
        int4 d4 = *(const int4*)(dst + i);
        atomicAdd(&scnt[d4.x >> 7], 1);
        atomicAdd(&scnt[d4.y >> 7], 1);
        atomicAdd(&scnt[d4.z >> 7], 1);
        atomicAdd(&scnt[d4.w >> 7], 1);
    }
    __syncthreads();
    int* row = cnt + (size_t)blockIdx.x * K;
    for (int b = t; b < K; b += 256) row[b] = scnt[b];
}

// ---------------------------------------------------------------------------
// 2b) part_scan: per bucket, exclusive scan of cnt over the NBB blocks
//     -> off[block][bucket], tot[bucket]
// ---------------------------------------------------------------------------
__global__ __launch_bounds__(NBB)
void part_scan_kernel(const int* __restrict__ cnt, int* __restrict__ off,
                      int* __restrict__ tot, int K) {
    __shared__ int s[NBB];
    int b = blockIdx.x;           // bucket
    int t = threadIdx.x;          // block index
    int v = cnt[(size_t)t * K + b];
    s[t] = v;
    __syncthreads();
    for (int o = 1; o < NBB; o <<= 1) {
        int x = (t >= o) ? s[t - o] : 0;
        __syncthreads();
        s[t] += x;
        __syncthreads();
    }
    off[(size_t)t * K + b] = s[t] - v;
    if (t == NBB - 1) tot[b] = s[t];
}

// ---------------------------------------------------------------------------
// 2c) part_scatter: scatter edges into gb using LDS cursors (no global atomics)
//     Entry = (local_dst << 16) | src
// ---------------------------------------------------------------------------
__global__ __launch_bounds__(256)
void part_scatter_kernel(const int* __restrict__ src, const int* __restrict__ dst,
                         const int* __restrict__ off, int* __restrict__ gb,
                         int E, int K, int ce) {
    __shared__ int slcur[800];
    int t = threadIdx.x;
    const int* orow = off + (size_t)blockIdx.x * K;
    for (int b = t; b < K; b += 256) slcur[b] = orow[b];
    __syncthreads();
    int e0 = blockIdx.x * ce;
    int e1 = min(E, e0 + ce);
    for (int i = e0 + t * 4; i < e1; i += 1024) {
        int4 d4 = *(const int4*)(dst + i);
        int4 s4 = *(const int4*)(src + i);
        int b0, p;
        b0 = d4.x >> 7; p = atomicAdd(&slcur[b0], 1);
        if (p < CAP) gb[(size_t)b0 * CAP + p] = (s4.x & 0xFFFF) | ((d4.x & 127) << 16);
        b0 = d4.y >> 7; p = atomicAdd(&slcur[b0], 1);
        if (p < CAP) gb[(size_t)b0 * CAP + p] = (s4.y & 0xFFFF) | ((d4.y & 127) << 16);
        b0 = d4.z >> 7; p = atomicAdd(&slcur[b0], 1);
        if (p < CAP) gb[(size_t)b0 * CAP + p] = (s4.z & 0xFFFF) | ((d4.z & 127) << 16);
        b0 = d4.w >> 7; p = atomicAdd(&slcur[b0], 1);
        if (p < CAP) gb[(size_t)b0 * CAP + p] = (s4.w & 0xFFFF) | ((d4.w & 127) << 16);
    }
}

// ---------------------------------------------------------------------------
// 3) fused: per bucket -- CSR in LDS, gather+mean (bf16, pk-f32 accum),
//    LDS transpose to A-frags, MFMA vs [Wl;Wr], relu, col-sum -> pgrid row.
// ---------------------------------------------------------------------------
__global__ __launch_bounds__(512, 4)
void fused_kernel(const ushort* __restrict__ xpb, const float* __restrict__ x_lig,
                  const int* __restrict__ gtot, const int* __restrict__ gb,
                  const ushort* __restrict__ wprep, const float* __restrict__ bvec,
                  float* __restrict__ pgrid, int N) {
    __shared__ int sdeg[BN];
    __shared__ int sstart[BN];
    __shared__ int scur[BN];
    __shared__ int ssc[BN];
    __shared__ int scsr[CAP];
    __shared__ unsigned sxrow[8][16][34];   // per-wave mean rows (bf16 pairs), padded
    __shared__ float sred[8][H];

    int b = blockIdx.x, t = threadIdx.x;
    int wv = t >> 6, lane = t & 63;
    int r = lane & 15, kg = lane >> 4;

    // --- early: issue x_lig loads (consumed in MFMA phase) ---
    int grow = b * BN + wv * 16 + r;
    bool gvalid = (grow < N);
    float4 va, vb, vc, vd;
    if (gvalid) {
        const float* xr = x_lig + (size_t)grow * D;
        va = *(const float4*)(xr + kg * 8);
        vb = *(const float4*)(xr + kg * 8 + 4);
        vc = *(const float4*)(xr + 32 + kg * 8);
        vd = *(const float4*)(xr + 32 + kg * 8 + 4);
    }

    int cnt = min(gtot[b], CAP);
    const int* mygb = gb + (size_t)b * CAP;

    // --- CSR build ---
    if (t < BN) sdeg[t] = 0;
    __syncthreads();
    for (int i = t; i < cnt; i += 512)
        atomicAdd(&sdeg[mygb[i] >> 16], 1);
    __syncthreads();
    if (t < BN) ssc[t] = sdeg[t];
    __syncthreads();
    for (int off = 1; off < BN; off <<= 1) {
        int v = 0;
        if (t < BN && t >= off) v = ssc[t - off];
        __syncthreads();
        if (t < BN) ssc[t] += v;
        __syncthreads();
    }
    if (t < BN) {
        int ex = ssc[t] - sdeg[t];
        sstart[t] = ex;
        scur[t] = ex;
    }
    __syncthreads();
    for (int i = t; i < cnt; i += 512) {
        int e = mygb[i];
        int p = atomicAdd(&scur[e >> 16], 1);
        scsr[p] = e & 0xFFFF;
    }
    __syncthreads();

    int sub = lane >> 3, part = lane & 7;

    // --- gather phase: wave wv owns local nodes wv*16 .. wv*16+15 ---
    for (int i = 0; i < 16; ++i) {
        int ln = wv * 16 + i;
        int s0 = sstart[ln], dg = sdeg[ln];
        f32x2 a[4];
        #pragma unroll
        for (int k = 0; k < 4; ++k) { a[k].x = 0.f; a[k].y = 0.f; }
        int j = sub;
        for (; j + 8 < dg; j += 16) {
            uint4 v0 = *(const uint4*)(xpb + (size_t)scsr[s0 + j] * D + part * 8);
            uint4 v1 = *(const uint4*)(xpb + (size_t)scsr[s0 + j + 8] * D + part * 8);
            a[0] += unp(v0.x); a[1] += unp(v0.y); a[2] += unp(v0.z); a[3] += unp(v0.w);
            a[0] += unp(v1.x); a[1] += unp(v1.y); a[2] += unp(v1.z); a[3] += unp(v1.w);
        }
        if (j < dg) {
            uint4 v0 = *(const uint4*)(xpb + (size_t)scsr[s0 + j] * D + part * 8);
            a[0] += unp(v0.x); a[1] += unp(v0.y); a[2] += unp(v0.z); a[3] += unp(v0.w);
        }
        #pragma unroll
        for (int k = 0; k < 4; ++k) {
            a[k].x += __shfl_xor(a[k].x, 8);  a[k].y += __shfl_xor(a[k].y, 8);
            a[k].x += __shfl_xor(a[k].x, 16); a[k].y += __shfl_xor(a[k].y, 16);
            a[k].x += __shfl_xor(a[k].x, 32); a[k].y += __shfl_xor(a[k].y, 32);
        }
        if (sub == 0) {
            float inv = 1.0f / fmaxf((float)dg, 1.0f);
            unsigned p0 = (unsigned)f2bf(a[0].x*inv) | ((unsigned)f2bf(a[0].y*inv) << 16);
            unsigned p1 = (unsigned)f2bf(a[1].x*inv) | ((unsigned)f2bf(a[1].y*inv) << 16);
            unsigned p2 = (unsigned)f2bf(a[2].x*inv) | ((unsigned)f2bf(a[2].y*inv) << 16);
            unsigned p3 = (unsigned)f2bf(a[3].x*inv) | ((unsigned)f2bf(a[3].y*inv) << 16);
            uint2* w2 = (uint2*)&sxrow[wv][i][part * 4];
            w2[0] = make_uint2(p0, p1);
            w2[1] = make_uint2(p2, p3);
        }
    }
    // (wave-local LDS write->read; no block barrier needed)

    // --- MFMA phase ---
    unsigned ua0[4], ua1[4];
    const unsigned* rp = &sxrow[wv][r][0];
    #pragma unroll
    for (int j2 = 0; j2 < 4; ++j2) {
        ua0[j2] = rp[kg * 4 + j2];
        ua1[j2] = rp[16 + kg * 4 + j2];
    }
    bf16x8 A0, A1;
    __builtin_memcpy(&A0, ua0, 16);
    __builtin_memcpy(&A1, ua1, 16);

    bf16x8 A2, A3;
    if (gvalid) {
        A2 = pack8(va, vb);
        A3 = pack8(vc, vd);
    } else {
        A2 = bf16x8{0,0,0,0,0,0,0,0};
        A3 = A2;
    }

    float hsum[8];
    bool full = (b * BN + wv * 16 + 16 <= N);
    const bf16x8* wp = (const bf16x8*)wprep;
    #pragma unroll 2
    for (int ht = 0; ht < 8; ++ht) {
        f32x4 acc = {0.f, 0.f, 0.f, 0.f};
        acc = __builtin_amdgcn_mfma_f32_16x16x32_bf16(A0, wp[(ht*4+0)*64 + lane], acc, 0, 0, 0);
        acc = __builtin_amdgcn_mfma_f32_16x16x32_bf16(A1, wp[(ht*4+1)*64 + lane], acc, 0, 0, 0);
        acc = __builtin_amdgcn_mfma_f32_16x16x32_bf16(A2, wp[(ht*4+2)*64 + lane], acc, 0, 0, 0);
        acc = __builtin_amdgcn_mfma_f32_16x16x32_bf16(A3, wp[(ht*4+3)*64 + lane], acc, 0, 0, 0);
        float bb = bvec[ht * 16 + r];
        float s = 0.f;
        if (full) {
            #pragma unroll
            for (int i = 0; i < 4; ++i) s += fmaxf(acc[i] + bb, 0.f);
        } else {
            #pragma unroll
            for (int i = 0; i < 4; ++i) {
                int row = b * BN + wv * 16 + kg * 4 + i;   // C/D: row=(lane>>4)*4+i
                if (row < N) s += fmaxf(acc[i] + bb, 0.f);
            }
        }
        hsum[ht] = s;
    }

    #pragma unroll
    for (int ht = 0; ht < 8; ++ht) {
        float v = hsum[ht];
        v += __shfl_xor(v, 16);
        v += __shfl_xor(v, 32);
        if (lane < 16) sred[wv][ht * 16 + lane] = v;
    }
    __syncthreads();
    if (t < H) {
        float s = 0.f;
        #pragma unroll
        for (int w = 0; w < 8; ++w) s += sred[w][t];
        pgrid[(size_t)b * H + t] = s;
    }
}

// ---------------------------------------------------------------------------
// 4) final reduce: sum pgrid rows, scale, dot with W_lin
// ---------------------------------------------------------------------------
__global__ void reduce_final_kernel(const float* __restrict__ pgrid, int nb,
                                    const float* __restrict__ W_lin,
                                    const float* __restrict__ b_lin,
                                    float* __restrict__ out, float invN) {
    __shared__ float sh[512];
    int t = threadIdx.x;
    int h = t & 127, q = t >> 7;
    float s = 0.f;
    for (int b = q; b < nb; b += 4) s += pgrid[(size_t)b * H + h];
    sh[t] = s;
    __syncthreads();
    if (q == 0) {
        float v = (sh[h] + sh[h + 128] + sh[h + 256] + sh[h + 384]) * invN * W_lin[h];
        sh[h] = v;
    }
    __syncthreads();
    if (t == 0) {
        float tot = b_lin[0];
        for (int i = 0; i < H; ++i) tot += sh[i];
        out[0] = tot;
    }
}

extern "C" void kernel_launch(void* const* d_in, const int* in_sizes, int n_in,
                              void* d_out, int out_size, void* d_ws, size_t ws_size,
                              hipStream_t stream) {
    const float* x_lig  = (const float*)d_in[0];
    const float* x_prot = (const float*)d_in[1];
    const float* W_l_pl = (const float*)d_in[5];
    const float* b_pl   = (const float*)d_in[6];
    const float* W_r_pl = (const float*)d_in[7];
    const float* W_lin  = (const float*)d_in[8];
    const float* b_lin  = (const float*)d_in[9];
    const int*   src_pl = (const int*)d_in[12];
    const int*   dst_pl = (const int*)d_in[13];

    int N  = in_sizes[0] / D;     // 100000
    int NP = in_sizes[1] / D;     // 50000
    int E  = in_sizes[12];        // 2000000
    int K  = (N + BN - 1) / BN;   // 782 buckets of 128 nodes

    char* base = (char*)d_ws;
    ushort* xpb   = (ushort*)base;  base += (size_t)NP * D * sizeof(ushort);   // 6.4 MB
    float* pgrid  = (float*)base;   base += (size_t)K * H * sizeof(float);     // 400 KB
    ushort* wprep = (ushort*)base;  base += (size_t)2048 * 8 * sizeof(ushort);
    int* cnt      = (int*)base;     base += (size_t)NBB * K * sizeof(int);     // 1.6 MB
    int* off      = (int*)base;     base += (size_t)NBB * K * sizeof(int);     // 1.6 MB
    int* tot      = (int*)base;     base += (size_t)K * sizeof(int);
    base = (char*)(((size_t)base + 255) & ~(size_t)255);
    int* gb       = (int*)base;     base += (size_t)K * CAP * sizeof(int);     // 10.8 MB

    int ce = ((E + NBB - 1) / NBB + 3) & ~3;   // edges per block, multiple of 4

    prep_w_kernel<<<8, 256, 0, stream>>>(W_l_pl, W_r_pl, wprep);
    prep_p_kernel<<<(NP * D / 8 + 255) / 256, 256, 0, stream>>>(x_prot, xpb, NP * D);
    part_hist_kernel<<<NBB, 256, 0, stream>>>(dst_pl, cnt, E, K, ce);
    part_scan_kernel<<<K, NBB, 0, stream>>>(cnt, off, tot, K);
    part_scatter_kernel<<<NBB, 256, 0, stream>>>(src_pl, dst_pl, off, gb, E, K, ce);
    fused_kernel<<<K, 512, 0, stream>>>(xpb, x_lig, tot, gb, wprep, b_pl, pgrid, N);
    reduce_final_kernel<<<1, 512, 0, stream>>>(pgrid, K, W_lin, b_lin,
                                               (float*)d_out, 1.0f / (float)N);
}

// Round 9
// 96.106 us; speedup vs baseline: 1.7384x; 1.7384x over previous
//
#include <hip/hip_runtime.h>

#define D 64
#define H 128
#define BN 128            // nodes per bucket
#define CAP 3456          // per-bucket edge capacity (avg 2558, +17 sigma)
#define NBB 256           // partition blocks
#define CE 7816           // edges per partition block (2M/256 rounded up to x8)

typedef short bf16x8 __attribute__((ext_vector_type(8)));
typedef float f32x4  __attribute__((ext_vector_type(4)));

__device__ __forceinline__ ushort f2bf(float f) {
    unsigned u = __float_as_uint(f);
    unsigned r = (u + 0x7FFFu + ((u >> 16) & 1u)) >> 16;
    return (ushort)r;
}

__device__ __forceinline__ bf16x8 pack8(float4 a, float4 b) {
    ushort o[8];
    o[0]=f2bf(a.x); o[1]=f2bf(a.y); o[2]=f2bf(a.z); o[3]=f2bf(a.w);
    o[4]=f2bf(b.x); o[5]=f2bf(b.y); o[6]=f2bf(b.z); o[7]=f2bf(b.w);
    bf16x8 r;
    __builtin_memcpy(&r, o, 16);
    return r;
}

// ---------------------------------------------------------------------------
// 1) stage1: fused prep_p + prep_w + per-block dst histogram (role by blockIdx)
// ---------------------------------------------------------------------------
__global__ __launch_bounds__(256)
void stage1_kernel(const float* __restrict__ xp, ushort* __restrict__ xpb, int totalp,
                   const float* __restrict__ Wl, const float* __restrict__ Wr,
                   ushort* __restrict__ wprep,
                   const int* __restrict__ dst, int* __restrict__ cnt,
                   int E, int K, int ce, int PB) {
    __shared__ int scnt[800];
    int bid = blockIdx.x;
    int t = threadIdx.x;
    if (bid < PB) {
        // prep_p: x_prot f32 -> bf16
        int i = (bid * 256 + t) * 8;
        if (i < totalp) {
            float4 a = *(const float4*)(xp + i);
            float4 b = *(const float4*)(xp + i + 4);
            bf16x8 v = pack8(a, b);
            *(bf16x8*)(xpb + i) = v;
        }
    } else if (bid < PB + 8) {
        // prep_w: pack [Wl;Wr] into MFMA B-frag layout
        int e = (bid - PB) * 256 + t;
        if (e < 2048) {
            int lane = e & 63;
            int ks = (e >> 6) & 3;
            int ht = e >> 8;
            int h = ht * 16 + (lane & 15);
            int k0 = ks * 32 + (lane >> 4) * 8;
            ushort o[8];
            #pragma unroll
            for (int j = 0; j < 8; ++j) {
                int k = k0 + j;
                float v = (k < D) ? Wl[k * H + h] : Wr[(k - D) * H + h];
                o[j] = f2bf(v);
            }
            *(bf16x8*)(wprep + (size_t)e * 8) = *(bf16x8*)o;
        }
    } else {
        // part_hist
        int blk = bid - PB - 8;
        for (int b = t; b < 800; b += 256) scnt[b] = 0;
        __syncthreads();
        int e0 = blk * ce;
        int e1 = min(E, e0 + ce);
        for (int i = e0 + t * 4; i < e1; i += 1024) {
            int4 d4 = *(const int4*)(dst + i);
            atomicAdd(&scnt[d4.x >> 7], 1);
            atomicAdd(&scnt[d4.y >> 7], 1);
            atomicAdd(&scnt[d4.z >> 7], 1);
            atomicAdd(&scnt[d4.w >> 7], 1);
        }
        __syncthreads();
        int* row = cnt + (size_t)blk * K;
        for (int b = t; b < K; b += 256) row[b] = scnt[b];
    }
}

// ---------------------------------------------------------------------------
// 2) part_scan: per bucket, exclusive scan of cnt over NBB blocks
// ---------------------------------------------------------------------------
__global__ __launch_bounds__(NBB)
void part_scan_kernel(const int* __restrict__ cnt, int* __restrict__ off,
                      int* __restrict__ tot, int K) {
    __shared__ int s[NBB];
    int b = blockIdx.x;           // bucket
    int t = threadIdx.x;          // block index
    int v = cnt[(size_t)t * K + b];
    s[t] = v;
    __syncthreads();
    for (int o = 1; o < NBB; o <<= 1) {
        int x = (t >= o) ? s[t - o] : 0;
        __syncthreads();
        s[t] += x;
        __syncthreads();
    }
    off[(size_t)t * K + b] = s[t] - v;
    if (t == NBB - 1) tot[b] = s[t];
}

// ---------------------------------------------------------------------------
// 3) part_scatter: in-LDS counting sort of the block's tile, then write out
//    in bucket order (coalesced runs). No global atomics.
//    Entry = (local_dst << 16) | src
// ---------------------------------------------------------------------------
__global__ __launch_bounds__(512)
void part_scatter_kernel(const int* __restrict__ src, const int* __restrict__ dst,
                         const int* __restrict__ off, int* __restrict__ gb,
                         int E, int K, int ce) {
    __shared__ int shist[800];
    __shared__ int sbase[800];
    __shared__ int gdelta[800];
    __shared__ int lcur[800];
    __shared__ int sscan[512];
    __shared__ int ebuf[CE];
    __shared__ unsigned short bkt[CE];

    int blk = blockIdx.x, t = threadIdx.x;
    int e0 = blk * ce;
    int e1 = min(E, e0 + ce);
    int myn = e1 - e0;

    for (int b = t; b < 800; b += 512) shist[b] = 0;
    __syncthreads();
    // pass 1: histogram
    for (int i = e0 + t * 4; i < e1; i += 2048) {
        int4 d4 = *(const int4*)(dst + i);
        atomicAdd(&shist[d4.x >> 7], 1);
        atomicAdd(&shist[d4.y >> 7], 1);
        atomicAdd(&shist[d4.z >> 7], 1);
        atomicAdd(&shist[d4.w >> 7], 1);
    }
    __syncthreads();
    // scan 800 buckets via 512 threads (2 buckets/thread for t<400)
    int c0 = 0, c1 = 0;
    if (t < 400) { c0 = shist[2 * t]; c1 = shist[2 * t + 1]; }
    int cs = c0 + c1;
    sscan[t] = (t < 400) ? cs : 0;
    __syncthreads();
    for (int o = 1; o < 512; o <<= 1) {
        int x = (t >= o) ? sscan[t - o] : 0;
        __syncthreads();
        sscan[t] += x;
        __syncthreads();
    }
    if (t < 400) {
        int ex = sscan[t] - cs;
        sbase[2 * t] = ex;
        sbase[2 * t + 1] = ex + c0;
    }
    __syncthreads();
    const int* orow = off + (size_t)blk * K;
    for (int b = t; b < K; b += 512) {
        int sb = sbase[b];
        gdelta[b] = orow[b] - sb;   // global_pos = gdelta[b] + sorted_p
        lcur[b] = sb;
    }
    __syncthreads();
    // pass 2: sort into LDS
    for (int i = e0 + t * 4; i < e1; i += 2048) {
        int4 d4 = *(const int4*)(dst + i);
        int4 s4 = *(const int4*)(src + i);
        int b, p;
        b = d4.x >> 7; p = atomicAdd(&lcur[b], 1);
        ebuf[p] = (s4.x & 0xFFFF) | ((d4.x & 127) << 16); bkt[p] = (unsigned short)b;
        b = d4.y >> 7; p = atomicAdd(&lcur[b], 1);
        ebuf[p] = (s4.y & 0xFFFF) | ((d4.y & 127) << 16); bkt[p] = (unsigned short)b;
        b = d4.z >> 7; p = atomicAdd(&lcur[b], 1);
        ebuf[p] = (s4.z & 0xFFFF) | ((d4.z & 127) << 16); bkt[p] = (unsigned short)b;
        b = d4.w >> 7; p = atomicAdd(&lcur[b], 1);
        ebuf[p] = (s4.w & 0xFFFF) | ((d4.w & 127) << 16); bkt[p] = (unsigned short)b;
    }
    __syncthreads();
    // pass 3: write out in bucket order -> coalesced runs within buckets
    for (int p = t; p < myn; p += 512) {
        int b = bkt[p];
        int loc = gdelta[b] + p;        // bucket-local position
        if (loc < CAP) gb[(size_t)b * CAP + loc] = ebuf[p];
    }
}

// ---------------------------------------------------------------------------
// 4) fused (round-7 body): per-bucket CSR in LDS, gather+mean, LDS transpose
//    to A-frags, MFMA vs [Wl;Wr], relu, col-sum -> pgrid row.
// ---------------------------------------------------------------------------
__global__ __launch_bounds__(512, 4)
void fused_kernel(const ushort* __restrict__ xpb, const float* __restrict__ x_lig,
                  const int* __restrict__ gtot, const int* __restrict__ gb,
                  const ushort* __restrict__ wprep, const float* __restrict__ bvec,
                  float* __restrict__ pgrid, int N) {
    __shared__ int sdeg[BN];
    __shared__ int sstart[BN];
    __shared__ int scur[BN];
    __shared__ int ssc[BN];
    __shared__ int scsr[CAP];
    __shared__ unsigned sxrow[8][16][34];
    __shared__ float sred[8][H];

    int b = blockIdx.x, t = threadIdx.x;
    int cnt = min(gtot[b], CAP);
    const int* mygb = gb + (size_t)b * CAP;

    // --- CSR build ---
    if (t < BN) sdeg[t] = 0;
    __syncthreads();
    for (int i = t; i < cnt; i += 512)
        atomicAdd(&sdeg[mygb[i] >> 16], 1);
    __syncthreads();
    if (t < BN) ssc[t] = sdeg[t];
    __syncthreads();
    for (int off = 1; off < BN; off <<= 1) {
        int v = 0;
        if (t < BN && t >= off) v = ssc[t - off];
        __syncthreads();
        if (t < BN) ssc[t] += v;
        __syncthreads();
    }
    if (t < BN) {
        int ex = ssc[t] - sdeg[t];
        sstart[t] = ex;
        scur[t] = ex;
    }
    __syncthreads();
    for (int i = t; i < cnt; i += 512) {
        int e = mygb[i];
        int p = atomicAdd(&scur[e >> 16], 1);
        scsr[p] = e & 0xFFFF;
    }
    __syncthreads();

    int wv = t >> 6, lane = t & 63;
    int sub = lane >> 3, part = lane & 7;

    // --- gather phase: wave wv owns local nodes wv*16 .. wv*16+15 ---
    for (int i = 0; i < 16; ++i) {
        int ln = wv * 16 + i;
        int s0 = sstart[ln], dg = sdeg[ln];
        float a[8] = {0.f,0.f,0.f,0.f,0.f,0.f,0.f,0.f};
        int j = sub;
        for (; j + 8 < dg; j += 16) {
            uint4 v0 = *(const uint4*)(xpb + (size_t)scsr[s0 + j] * D + part * 8);
            uint4 v1 = *(const uint4*)(xpb + (size_t)scsr[s0 + j + 8] * D + part * 8);
            a[0] += __uint_as_float(v0.x << 16); a[1] += __uint_as_float(v0.x & 0xFFFF0000u);
            a[2] += __uint_as_float(v0.y << 16); a[3] += __uint_as_float(v0.y & 0xFFFF0000u);
            a[4] += __uint_as_float(v0.z << 16); a[5] += __uint_as_float(v0.z & 0xFFFF0000u);
            a[6] += __uint_as_float(v0.w << 16); a[7] += __uint_as_float(v0.w & 0xFFFF0000u);
            a[0] += __uint_as_float(v1.x << 16); a[1] += __uint_as_float(v1.x & 0xFFFF0000u);
            a[2] += __uint_as_float(v1.y << 16); a[3] += __uint_as_float(v1.y & 0xFFFF0000u);
            a[4] += __uint_as_float(v1.z << 16); a[5] += __uint_as_float(v1.z & 0xFFFF0000u);
            a[6] += __uint_as_float(v1.w << 16); a[7] += __uint_as_float(v1.w & 0xFFFF0000u);
        }
        if (j < dg) {
            uint4 v0 = *(const uint4*)(xpb + (size_t)scsr[s0 + j] * D + part * 8);
            a[0] += __uint_as_float(v0.x << 16); a[1] += __uint_as_float(v0.x & 0xFFFF0000u);
            a[2] += __uint_as_float(v0.y << 16); a[3] += __uint_as_float(v0.y & 0xFFFF0000u);
            a[4] += __uint_as_float(v0.z << 16); a[5] += __uint_as_float(v0.z & 0xFFFF0000u);
            a[6] += __uint_as_float(v0.w << 16); a[7] += __uint_as_float(v0.w & 0xFFFF0000u);
        }
        #pragma unroll
        for (int k = 0; k < 8; ++k) {
            a[k] += __shfl_xor(a[k], 8);
            a[k] += __shfl_xor(a[k], 16);
            a[k] += __shfl_xor(a[k], 32);
        }
        if (sub == 0) {
            float inv = 1.0f / fmaxf((float)dg, 1.0f);
            unsigned p0 = (unsigned)f2bf(a[0]*inv) | ((unsigned)f2bf(a[1]*inv) << 16);
            unsigned p1 = (unsigned)f2bf(a[2]*inv) | ((unsigned)f2bf(a[3]*inv) << 16);
            unsigned p2 = (unsigned)f2bf(a[4]*inv) | ((unsigned)f2bf(a[5]*inv) << 16);
            unsigned p3 = (unsigned)f2bf(a[6]*inv) | ((unsigned)f2bf(a[7]*inv) << 16);
            uint2* w2 = (uint2*)&sxrow[wv][i][part * 4];
            w2[0] = make_uint2(p0, p1);
            w2[1] = make_uint2(p2, p3);
        }
    }
    // (wave-local LDS write->read; no block barrier needed)

    // --- MFMA phase ---
    int r = lane & 15, kg = lane >> 4;

    unsigned ua0[4], ua1[4];
    const unsigned* rp = &sxrow[wv][r][0];
    #pragma unroll
    for (int j2 = 0; j2 < 4; ++j2) {
        ua0[j2] = rp[kg * 4 + j2];
        ua1[j2] = rp[16 + kg * 4 + j2];
    }
    bf16x8 A0, A1;
    __builtin_memcpy(&A0, ua0, 16);
    __builtin_memcpy(&A1, ua1, 16);

    int grow = b * BN + wv * 16 + r;
    bf16x8 A2, A3;
    if (grow < N) {
        const float* xr = x_lig + (size_t)grow * D;
        float4 va = *(const float4*)(xr + kg * 8);
        float4 vb = *(const float4*)(xr + kg * 8 + 4);
        A2 = pack8(va, vb);
        float4 vc = *(const float4*)(xr + 32 + kg * 8);
        float4 vd = *(const float4*)(xr + 32 + kg * 8 + 4);
        A3 = pack8(vc, vd);
    } else {
        A2 = bf16x8{0,0,0,0,0,0,0,0};
        A3 = A2;
    }

    float hsum[8];
    bool full = (b * BN + wv * 16 + 16 <= N);
    const bf16x8* wp = (const bf16x8*)wprep;
    #pragma unroll 2
    for (int ht = 0; ht < 8; ++ht) {
        f32x4 acc = {0.f, 0.f, 0.f, 0.f};
        acc = __builtin_amdgcn_mfma_f32_16x16x32_bf16(A0, wp[(ht*4+0)*64 + lane], acc, 0, 0, 0);
        acc = __builtin_amdgcn_mfma_f32_16x16x32_bf16(A1, wp[(ht*4+1)*64 + lane], acc, 0, 0, 0);
        acc = __builtin_amdgcn_mfma_f32_16x16x32_bf16(A2, wp[(ht*4+2)*64 + lane], acc, 0, 0, 0);
        acc = __builtin_amdgcn_mfma_f32_16x16x32_bf16(A3, wp[(ht*4+3)*64 + lane], acc, 0, 0, 0);
        float bb = bvec[ht * 16 + r];
        float s = 0.f;
        if (full) {
            #pragma unroll
            for (int i = 0; i < 4; ++i) s += fmaxf(acc[i] + bb, 0.f);
        } else {
            #pragma unroll
            for (int i = 0; i < 4; ++i) {
                int row = b * BN + wv * 16 + kg * 4 + i;   // C/D: row=(lane>>4)*4+i
                if (row < N) s += fmaxf(acc[i] + bb, 0.f);
            }
        }
        hsum[ht] = s;
    }

    #pragma unroll
    for (int ht = 0; ht < 8; ++ht) {
        float v = hsum[ht];
        v += __shfl_xor(v, 16);
        v += __shfl_xor(v, 32);
        if (lane < 16) sred[wv][ht * 16 + lane] = v;
    }
    __syncthreads();
    if (t < H) {
        float s = 0.f;
        #pragma unroll
        for (int w = 0; w < 8; ++w) s += sred[w][t];
        pgrid[(size_t)b * H + t] = s;
    }
}

// ---------------------------------------------------------------------------
// 5) reduce1: 64 blocks sum pgrid rows -> pgrid2[64][H]
// ---------------------------------------------------------------------------
__global__ __launch_bounds__(128)
void reduce1_kernel(const float* __restrict__ pgrid, int nb, float* __restrict__ pgrid2) {
    int t = threadIdx.x;
    float s = 0.f;
    for (int r = blockIdx.x; r < nb; r += 64) s += pgrid[(size_t)r * H + t];
    pgrid2[(size_t)blockIdx.x * H + t] = s;
}

// ---------------------------------------------------------------------------
// 6) head: out = (sum(pgrid2)/N) @ W_lin + b_lin
// ---------------------------------------------------------------------------
__global__ __launch_bounds__(128)
void head_kernel(const float* __restrict__ pgrid2,
                 const float* __restrict__ W_lin, const float* __restrict__ b_lin,
                 float* __restrict__ out, float invN) {
    __shared__ float sh[H];
    int t = threadIdx.x;
    float s = 0.f;
    #pragma unroll 8
    for (int r = 0; r < 64; ++r) s += pgrid2[(size_t)r * H + t];
    sh[t] = s * invN * W_lin[t];
    __syncthreads();
    if (t == 0) {
        float tot = b_lin[0];
        for (int i = 0; i < H; ++i) tot += sh[i];
        out[0] = tot;
    }
}

extern "C" void kernel_launch(void* const* d_in, const int* in_sizes, int n_in,
                              void* d_out, int out_size, void* d_ws, size_t ws_size,
                              hipStream_t stream) {
    const float* x_lig  = (const float*)d_in[0];
    const float* x_prot = (const float*)d_in[1];
    const float* W_l_pl = (const float*)d_in[5];
    const float* b_pl   = (const float*)d_in[6];
    const float* W_r_pl = (const float*)d_in[7];
    const float* W_lin  = (const float*)d_in[8];
    const float* b_lin  = (const float*)d_in[9];
    const int*   src_pl = (const int*)d_in[12];
    const int*   dst_pl = (const int*)d_in[13];

    int N  = in_sizes[0] / D;     // 100000
    int NP = in_sizes[1] / D;     // 50000
    int E  = in_sizes[12];        // 2000000
    int K  = (N + BN - 1) / BN;   // 782 buckets of 128 nodes

    char* base = (char*)d_ws;
    ushort* xpb   = (ushort*)base;  base += (size_t)NP * D * sizeof(ushort);   // 6.4 MB
    float* pgrid  = (float*)base;   base += (size_t)K * H * sizeof(float);     // 400 KB
    float* pgrid2 = (float*)base;   base += (size_t)64 * H * sizeof(float);    // 32 KB
    ushort* wprep = (ushort*)base;  base += (size_t)2048 * 8 * sizeof(ushort);
    int* cnt      = (int*)base;     base += (size_t)NBB * K * sizeof(int);     // 800 KB
    int* off      = (int*)base;     base += (size_t)NBB * K * sizeof(int);     // 800 KB
    int* tot      = (int*)base;     base += (size_t)K * sizeof(int);
    base = (char*)(((size_t)base + 255) & ~(size_t)255);
    int* gb       = (int*)base;     base += (size_t)K * CAP * sizeof(int);     // 10.8 MB

    int ce = ((E + NBB - 1) / NBB + 3) & ~3;   // 7816, multiple of 4, <= CE
    int PB = (NP * D / 8 + 255) / 256;         // prep_p blocks

    stage1_kernel<<<PB + 8 + NBB, 256, 0, stream>>>(x_prot, xpb, NP * D,
                                                    W_l_pl, W_r_pl, wprep,
                                                    dst_pl, cnt, E, K, ce, PB);
    part_scan_kernel<<<K, NBB, 0, stream>>>(cnt, off, tot, K);
    part_scatter_kernel<<<NBB, 512, 0, stream>>>(src_pl, dst_pl, off, gb, E, K, ce);
    fused_kernel<<<K, 512, 0, stream>>>(xpb, x_lig, tot, gb, wprep, b_pl, pgrid, N);
    reduce1_kernel<<<64, 128, 0, stream>>>(pgrid, K, pgrid2);
    head_kernel<<<1, 128, 0, stream>>>(pgrid2, W_lin, b_lin, (float*)d_out,
                                       1.0f / (float)N);
}

// Round 10
// 95.935 us; speedup vs baseline: 1.7415x; 1.0018x over previous
//
#include <hip/hip_runtime.h>

#define D 64
#define H 128
#define BN 128            // nodes per bucket
#define CAP 3456          // per-bucket edge capacity (avg 2558, +17 sigma)
#define NBB 256           // partition blocks
#define CE 7816           // edges per partition block (2M/256 rounded up to x8)

typedef short bf16x8 __attribute__((ext_vector_type(8)));
typedef float f32x4  __attribute__((ext_vector_type(4)));

__device__ __forceinline__ ushort f2bf(float f) {
    unsigned u = __float_as_uint(f);
    unsigned r = (u + 0x7FFFu + ((u >> 16) & 1u)) >> 16;
    return (ushort)r;
}

__device__ __forceinline__ bf16x8 pack8(float4 a, float4 b) {
    ushort o[8];
    o[0]=f2bf(a.x); o[1]=f2bf(a.y); o[2]=f2bf(a.z); o[3]=f2bf(a.w);
    o[4]=f2bf(b.x); o[5]=f2bf(b.y); o[6]=f2bf(b.z); o[7]=f2bf(b.w);
    bf16x8 r;
    __builtin_memcpy(&r, o, 16);
    return r;
}

// accumulate 8 packed bf16 (uint4) into 8 f32
__device__ __forceinline__ void accu(float* a, uint4 v) {
    a[0] += __uint_as_float(v.x << 16); a[1] += __uint_as_float(v.x & 0xFFFF0000u);
    a[2] += __uint_as_float(v.y << 16); a[3] += __uint_as_float(v.y & 0xFFFF0000u);
    a[4] += __uint_as_float(v.z << 16); a[5] += __uint_as_float(v.z & 0xFFFF0000u);
    a[6] += __uint_as_float(v.w << 16); a[7] += __uint_as_float(v.w & 0xFFFF0000u);
}

// ---------------------------------------------------------------------------
// 1) stage1: fused prep_p + prep_w + per-block dst histogram (role by blockIdx)
// ---------------------------------------------------------------------------
__global__ __launch_bounds__(256)
void stage1_kernel(const float* __restrict__ xp, ushort* __restrict__ xpb, int totalp,
                   const float* __restrict__ Wl, const float* __restrict__ Wr,
                   ushort* __restrict__ wprep,
                   const int* __restrict__ dst, int* __restrict__ cnt,
                   int E, int K, int ce, int PB) {
    __shared__ int scnt[800];
    int bid = blockIdx.x;
    int t = threadIdx.x;
    if (bid < PB) {
        // prep_p: x_prot f32 -> bf16
        int i = (bid * 256 + t) * 8;
        if (i < totalp) {
            float4 a = *(const float4*)(xp + i);
            float4 b = *(const float4*)(xp + i + 4);
            bf16x8 v = pack8(a, b);
            *(bf16x8*)(xpb + i) = v;
        }
    } else if (bid < PB + 8) {
        // prep_w: pack [Wl;Wr] into MFMA B-frag layout
        int e = (bid - PB) * 256 + t;
        if (e < 2048) {
            int lane = e & 63;
            int ks = (e >> 6) & 3;
            int ht = e >> 8;
            int h = ht * 16 + (lane & 15);
            int k0 = ks * 32 + (lane >> 4) * 8;
            ushort o[8];
            #pragma unroll
            for (int j = 0; j < 8; ++j) {
                int k = k0 + j;
                float v = (k < D) ? Wl[k * H + h] : Wr[(k - D) * H + h];
                o[j] = f2bf(v);
            }
            *(bf16x8*)(wprep + (size_t)e * 8) = *(bf16x8*)o;
        }
    } else {
        // part_hist
        int blk = bid - PB - 8;
        for (int b = t; b < 800; b += 256) scnt[b] = 0;
        __syncthreads();
        int e0 = blk * ce;
        int e1 = min(E, e0 + ce);
        for (int i = e0 + t * 4; i < e1; i += 1024) {
            int4 d4 = *(const int4*)(dst + i);
            atomicAdd(&scnt[d4.x >> 7], 1);
            atomicAdd(&scnt[d4.y >> 7], 1);
            atomicAdd(&scnt[d4.z >> 7], 1);
            atomicAdd(&scnt[d4.w >> 7], 1);
        }
        __syncthreads();
        int* row = cnt + (size_t)blk * K;
        for (int b = t; b < K; b += 256) row[b] = scnt[b];
    }
}

// ---------------------------------------------------------------------------
// 2) part_scan: per bucket, exclusive scan of cnt over NBB blocks
// ---------------------------------------------------------------------------
__global__ __launch_bounds__(NBB)
void part_scan_kernel(const int* __restrict__ cnt, int* __restrict__ off,
                      int* __restrict__ tot, int K) {
    __shared__ int s[NBB];
    int b = blockIdx.x;           // bucket
    int t = threadIdx.x;          // block index
    int v = cnt[(size_t)t * K + b];
    s[t] = v;
    __syncthreads();
    for (int o = 1; o < NBB; o <<= 1) {
        int x = (t >= o) ? s[t - o] : 0;
        __syncthreads();
        s[t] += x;
        __syncthreads();
    }
    off[(size_t)t * K + b] = s[t] - v;
    if (t == NBB - 1) tot[b] = s[t];
}

// ---------------------------------------------------------------------------
// 3) part_scatter: in-LDS counting sort of the block's tile, then write out
//    in bucket order (coalesced runs). No global atomics.
//    Entry = (local_dst << 16) | src
// ---------------------------------------------------------------------------
__global__ __launch_bounds__(512)
void part_scatter_kernel(const int* __restrict__ src, const int* __restrict__ dst,
                         const int* __restrict__ off, int* __restrict__ gb,
                         int E, int K, int ce) {
    __shared__ int shist[800];
    __shared__ int sbase[800];
    __shared__ int gdelta[800];
    __shared__ int lcur[800];
    __shared__ int sscan[512];
    __shared__ int ebuf[CE];
    __shared__ unsigned short bkt[CE];

    int blk = blockIdx.x, t = threadIdx.x;
    int e0 = blk * ce;
    int e1 = min(E, e0 + ce);
    int myn = e1 - e0;

    for (int b = t; b < 800; b += 512) shist[b] = 0;
    __syncthreads();
    // pass 1: histogram
    for (int i = e0 + t * 4; i < e1; i += 2048) {
        int4 d4 = *(const int4*)(dst + i);
        atomicAdd(&shist[d4.x >> 7], 1);
        atomicAdd(&shist[d4.y >> 7], 1);
        atomicAdd(&shist[d4.z >> 7], 1);
        atomicAdd(&shist[d4.w >> 7], 1);
    }
    __syncthreads();
    // scan 800 buckets via 512 threads (2 buckets/thread for t<400)
    int c0 = 0, c1 = 0;
    if (t < 400) { c0 = shist[2 * t]; c1 = shist[2 * t + 1]; }
    int cs = c0 + c1;
    sscan[t] = (t < 400) ? cs : 0;
    __syncthreads();
    for (int o = 1; o < 512; o <<= 1) {
        int x = (t >= o) ? sscan[t - o] : 0;
        __syncthreads();
        sscan[t] += x;
        __syncthreads();
    }
    if (t < 400) {
        int ex = sscan[t] - cs;
        sbase[2 * t] = ex;
        sbase[2 * t + 1] = ex + c0;
    }
    __syncthreads();
    const int* orow = off + (size_t)blk * K;
    for (int b = t; b < K; b += 512) {
        int sb = sbase[b];
        gdelta[b] = orow[b] - sb;   // global_pos = gdelta[b] + sorted_p
        lcur[b] = sb;
    }
    __syncthreads();
    // pass 2: sort into LDS
    for (int i = e0 + t * 4; i < e1; i += 2048) {
        int4 d4 = *(const int4*)(dst + i);
        int4 s4 = *(const int4*)(src + i);
        int b, p;
        b = d4.x >> 7; p = atomicAdd(&lcur[b], 1);
        ebuf[p] = (s4.x & 0xFFFF) | ((d4.x & 127) << 16); bkt[p] = (unsigned short)b;
        b = d4.y >> 7; p = atomicAdd(&lcur[b], 1);
        ebuf[p] = (s4.y & 0xFFFF) | ((d4.y & 127) << 16); bkt[p] = (unsigned short)b;
        b = d4.z >> 7; p = atomicAdd(&lcur[b], 1);
        ebuf[p] = (s4.z & 0xFFFF) | ((d4.z & 127) << 16); bkt[p] = (unsigned short)b;
        b = d4.w >> 7; p = atomicAdd(&lcur[b], 1);
        ebuf[p] = (s4.w & 0xFFFF) | ((d4.w & 127) << 16); bkt[p] = (unsigned short)b;
    }
    __syncthreads();
    // pass 3: write out in bucket order -> coalesced runs within buckets
    for (int p = t; p < myn; p += 512) {
        int b = bkt[p];
        int loc = gdelta[b] + p;        // bucket-local position
        if (loc < CAP) gb[(size_t)b * CAP + loc] = ebuf[p];
    }
}

// ---------------------------------------------------------------------------
// 4) fused: per-bucket CSR in LDS, then lane-per-(node,elem-slice) gather that
//    lands DIRECTLY in MFMA A-frag registers (no shfl, no LDS transpose),
//    MFMA vs [Wl;Wr], relu, col-sum -> pgrid row.
// ---------------------------------------------------------------------------
__global__ __launch_bounds__(512, 4)
void fused_kernel(const ushort* __restrict__ xpb, const float* __restrict__ x_lig,
                  const int* __restrict__ gtot, const int* __restrict__ gb,
                  const ushort* __restrict__ wprep, const float* __restrict__ bvec,
                  float* __restrict__ pgrid, int N) {
    __shared__ int sdeg[BN];
    __shared__ int sstart[BN];
    __shared__ int scur[BN];
    __shared__ int ssc[BN];
    __shared__ int scsr[CAP];
    __shared__ float sred[8][H];

    int b = blockIdx.x, t = threadIdx.x;
    int cnt = min(gtot[b], CAP);
    const int* mygb = gb + (size_t)b * CAP;

    // --- CSR build ---
    if (t < BN) sdeg[t] = 0;
    __syncthreads();
    for (int i = t; i < cnt; i += 512)
        atomicAdd(&sdeg[mygb[i] >> 16], 1);
    __syncthreads();
    if (t < BN) ssc[t] = sdeg[t];
    __syncthreads();
    for (int off = 1; off < BN; off <<= 1) {
        int v = 0;
        if (t < BN && t >= off) v = ssc[t - off];
        __syncthreads();
        if (t < BN) ssc[t] += v;
        __syncthreads();
    }
    if (t < BN) {
        int ex = ssc[t] - sdeg[t];
        sstart[t] = ex;
        scur[t] = ex;
    }
    __syncthreads();
    for (int i = t; i < cnt; i += 512) {
        int e = mygb[i];
        int p = atomicAdd(&scur[e >> 16], 1);
        scsr[p] = e & 0xFFFF;
    }
    __syncthreads();

    int wv = t >> 6, lane = t & 63;
    int r = lane & 15, kg = lane >> 4;

    // --- gather: lane owns node wv*16+r, elements [kg*8..+7] and [32+kg*8..+7].
    //     Accumulators ARE the A-fragment (up to scale+convert).
    int ln = wv * 16 + r;
    int s0 = sstart[ln], dg = sdeg[ln];
    float a0[8] = {0.f,0.f,0.f,0.f,0.f,0.f,0.f,0.f};
    float a1[8] = {0.f,0.f,0.f,0.f,0.f,0.f,0.f,0.f};
    int j = 0;
    for (; j + 1 < dg; j += 2) {
        int i0 = scsr[s0 + j];
        int i1 = scsr[s0 + j + 1];
        const ushort* r0 = xpb + (size_t)i0 * D + kg * 8;
        const ushort* r1 = xpb + (size_t)i1 * D + kg * 8;
        uint4 u0 = *(const uint4*)(r0);
        uint4 u1 = *(const uint4*)(r0 + 32);
        uint4 w0 = *(const uint4*)(r1);
        uint4 w1 = *(const uint4*)(r1 + 32);
        accu(a0, u0); accu(a1, u1);
        accu(a0, w0); accu(a1, w1);
    }
    if (j < dg) {
        int i0 = scsr[s0 + j];
        const ushort* r0 = xpb + (size_t)i0 * D + kg * 8;
        uint4 u0 = *(const uint4*)(r0);
        uint4 u1 = *(const uint4*)(r0 + 32);
        accu(a0, u0); accu(a1, u1);
    }

    float inv = 1.0f / fmaxf((float)dg, 1.0f);
    ushort o0[8], o1[8];
    #pragma unroll
    for (int k = 0; k < 8; ++k) {
        o0[k] = f2bf(a0[k] * inv);
        o1[k] = f2bf(a1[k] * inv);
    }
    bf16x8 A0, A1;
    __builtin_memcpy(&A0, o0, 16);
    __builtin_memcpy(&A1, o1, 16);

    // --- x_lig A-frags direct from global (f32 -> bf16) ---
    int grow = b * BN + wv * 16 + r;
    bf16x8 A2, A3;
    if (grow < N) {
        const float* xr = x_lig + (size_t)grow * D;
        float4 va = *(const float4*)(xr + kg * 8);
        float4 vb = *(const float4*)(xr + kg * 8 + 4);
        A2 = pack8(va, vb);
        float4 vc = *(const float4*)(xr + 32 + kg * 8);
        float4 vd = *(const float4*)(xr + 32 + kg * 8 + 4);
        A3 = pack8(vc, vd);
    } else {
        A2 = bf16x8{0,0,0,0,0,0,0,0};
        A3 = A2;
    }

    // --- MFMA phase ---
    float hsum[8];
    bool full = (b * BN + wv * 16 + 16 <= N);
    const bf16x8* wp = (const bf16x8*)wprep;
    #pragma unroll 2
    for (int ht = 0; ht < 8; ++ht) {
        f32x4 acc = {0.f, 0.f, 0.f, 0.f};
        acc = __builtin_amdgcn_mfma_f32_16x16x32_bf16(A0, wp[(ht*4+0)*64 + lane], acc, 0, 0, 0);
        acc = __builtin_amdgcn_mfma_f32_16x16x32_bf16(A1, wp[(ht*4+1)*64 + lane], acc, 0, 0, 0);
        acc = __builtin_amdgcn_mfma_f32_16x16x32_bf16(A2, wp[(ht*4+2)*64 + lane], acc, 0, 0, 0);
        acc = __builtin_amdgcn_mfma_f32_16x16x32_bf16(A3, wp[(ht*4+3)*64 + lane], acc, 0, 0, 0);
        float bb = bvec[ht * 16 + r];
        float s = 0.f;
        if (full) {
            #pragma unroll
            for (int i = 0; i < 4; ++i) s += fmaxf(acc[i] + bb, 0.f);
        } else {
            #pragma unroll
            for (int i = 0; i < 4; ++i) {
                int row = b * BN + wv * 16 + kg * 4 + i;   // C/D: row=(lane>>4)*4+i
                if (row < N) s += fmaxf(acc[i] + bb, 0.f);
            }
        }
        hsum[ht] = s;
    }

    #pragma unroll
    for (int ht = 0; ht < 8; ++ht) {
        float v = hsum[ht];
        v += __shfl_xor(v, 16);
        v += __shfl_xor(v, 32);
        if (lane < 16) sred[wv][ht * 16 + lane] = v;
    }
    __syncthreads();
    if (t < H) {
        float s = 0.f;
        #pragma unroll
        for (int w = 0; w < 8; ++w) s += sred[w][t];
        pgrid[(size_t)b * H + t] = s;
    }
}

// ---------------------------------------------------------------------------
// 5) reduce1: 64 blocks sum pgrid rows -> pgrid2[64][H]
// ---------------------------------------------------------------------------
__global__ __launch_bounds__(128)
void reduce1_kernel(const float* __restrict__ pgrid, int nb, float* __restrict__ pgrid2) {
    int t = threadIdx.x;
    float s = 0.f;
    for (int r = blockIdx.x; r < nb; r += 64) s += pgrid[(size_t)r * H + t];
    pgrid2[(size_t)blockIdx.x * H + t] = s;
}

// ---------------------------------------------------------------------------
// 6) head: out = (sum(pgrid2)/N) @ W_lin + b_lin
// ---------------------------------------------------------------------------
__global__ __launch_bounds__(128)
void head_kernel(const float* __restrict__ pgrid2,
                 const float* __restrict__ W_lin, const float* __restrict__ b_lin,
                 float* __restrict__ out, float invN) {
    __shared__ float sh[H];
    int t = threadIdx.x;
    float s = 0.f;
    #pragma unroll 8
    for (int r = 0; r < 64; ++r) s += pgrid2[(size_t)r * H + t];
    sh[t] = s * invN * W_lin[t];
    __syncthreads();
    if (t == 0) {
        float tot = b_lin[0];
        for (int i = 0; i < H; ++i) tot += sh[i];
        out[0] = tot;
    }
}

extern "C" void kernel_launch(void* const* d_in, const int* in_sizes, int n_in,
                              void* d_out, int out_size, void* d_ws, size_t ws_size,
                              hipStream_t stream) {
    const float* x_lig  = (const float*)d_in[0];
    const float* x_prot = (const float*)d_in[1];
    const float* W_l_pl = (const float*)d_in[5];
    const float* b_pl   = (const float*)d_in[6];
    const float* W_r_pl = (const float*)d_in[7];
    const float* W_lin  = (const float*)d_in[8];
    const float* b_lin  = (const float*)d_in[9];
    const int*   src_pl = (const int*)d_in[12];
    const int*   dst_pl = (const int*)d_in[13];

    int N  = in_sizes[0] / D;     // 100000
    int NP = in_sizes[1] / D;     // 50000
    int E  = in_sizes[12];        // 2000000
    int K  = (N + BN - 1) / BN;   // 782 buckets of 128 nodes

    char* base = (char*)d_ws;
    ushort* xpb   = (ushort*)base;  base += (size_t)NP * D * sizeof(ushort);   // 6.4 MB
    float* pgrid  = (float*)base;   base += (size_t)K * H * sizeof(float);     // 400 KB
    float* pgrid2 = (float*)base;   base += (size_t)64 * H * sizeof(float);    // 32 KB
    ushort* wprep = (ushort*)base;  base += (size_t)2048 * 8 * sizeof(ushort);
    int* cnt      = (int*)base;     base += (size_t)NBB * K * sizeof(int);     // 800 KB
    int* off      = (int*)base;     base += (size_t)NBB * K * sizeof(int);     // 800 KB
    int* tot      = (int*)base;     base += (size_t)K * sizeof(int);
    base = (char*)(((size_t)base + 255) & ~(size_t)255);
    int* gb       = (int*)base;     base += (size_t)K * CAP * sizeof(int);     // 10.8 MB

    int ce = ((E + NBB - 1) / NBB + 3) & ~3;   // 7816, multiple of 4, <= CE
    int PB = (NP * D / 8 + 255) / 256;         // prep_p blocks

    stage1_kernel<<<PB + 8 + NBB, 256, 0, stream>>>(x_prot, xpb, NP * D,
                                                    W_l_pl, W_r_pl, wprep,
                                                    dst_pl, cnt, E, K, ce, PB);
    part_scan_kernel<<<K, NBB, 0, stream>>>(cnt, off, tot, K);
    part_scatter_kernel<<<NBB, 512, 0, stream>>>(src_pl, dst_pl, off, gb, E, K, ce);
    fused_kernel<<<K, 512, 0, stream>>>(xpb, x_lig, tot, gb, wprep, b_pl, pgrid, N);
    reduce1_kernel<<<64, 128, 0, stream>>>(pgrid, K, pgrid2);
    head_kernel<<<1, 128, 0, stream>>>(pgrid2, W_lin, b_lin, (float*)d_out,
                                       1.0f / (float)N);
}